// Round 6
// baseline (317.677 us; speedup 1.0000x reference)
//
#include <hip/hip_runtime.h>

#define BATCH 64
#define M_GT  100
#define M1    101
#define NANCH 8732
#define BLOCK 256
#define NPT   2                    // anchors per thread -> dwordx2 stores
#define NTILE (BLOCK * NPT)        // 512
#define NX    18                   // ceil(8732/512)
#define NBLK  (NX * BATCH)         // 1152 blocks = 4608 waves
#define NXCD  8
#define GROUP 8                    // rows per store burst
#define MBULK ((M1 / GROUP) * GROUP)   // 96
#define MTAIL (M1 - MBULK)             // 5

// Journal:
//  R0: NPT=4, 576 blocks                    -> 245.7 (baseline)
//  R1: NPT=2, depth-8 groups, 1152 blocks   -> 244.4 neutral
//  R2: nontemporal stores                   -> 279.3 REGRESSION (L2 merge load-bearing)
//  R3: XCD-grouping swizzle                 -> 240.4 (+4, best)
//  R4: role-split contiguous row writer     -> 265.8 REGRESSION (contiguity not the lever)
//  R5: double compute+store pass            -> 264.8 => marginal pass = 24.4 µs;
//      237MB output fits L3 (rewrites free) => kernel ~= 24 compute + ~75 memory
//  R6 (this): DIAGNOSTIC v2. R3 kernel identical through its store phase,
//  then 3 compute-only replica passes (opaque-z anti-CSE, asm sinks anti-DCE)
//  to stretch the kernel past the 141-µs fill cutoff and finally read its
//  own FETCH_SIZE / WRITE_SIZE / VALUBusy row. Store stream unchanged.
__global__ __launch_bounds__(BLOCK) void encode_fused(
    const float* __restrict__ labels,   // [B, M, 5]
    const float* __restrict__ dboxes,   // [N, 4]
    float* __restrict__ out_labeled,    // [B, N, 5]
    float* __restrict__ out_ious)       // [B, M1, N]
{
    __shared__ float4 s_box[M1];
    __shared__ float  s_ar[M1], s_cls[M1];

    const int tid = threadIdx.x;
    // XCD-grouping swizzle (R3): all NX chunks of each b on one XCD.
    const int x  = blockIdx.x % NXCD;
    const int j  = blockIdx.x / NXCD;
    const int b  = x * (BATCH / NXCD) + j / NX;
    const int nb = j % NX;

    if (tid < M1) {
        float x1 = 0.f, y1 = 0.f, x2 = 0.f, y2 = 0.f, cls = 0.f;
        float ar = __builtin_inff();   // pad/invalid -> iou = inter*rcp(inf) = +0
        if (tid >= 1) {
            const float* row = labels + ((size_t)b * M_GT + (tid - 1)) * 5;
            x1 = row[0]; y1 = row[1]; x2 = row[2]; y2 = row[3]; cls = row[4];
            if (cls != 0.0f) ar = (x2 - x1) * (y2 - y1);
        }
        s_box[tid] = make_float4(x1, y1, x2, y2);
        s_ar[tid] = ar; s_cls[tid] = cls;
    }
    __syncthreads();

    const int n0 = nb * NTILE + tid * NPT;
    if (n0 >= NANCH) return;

    float ax1[NPT], ay1[NPT], ax2[NPT], ay2[NPT], aa[NPT];
    #pragma unroll
    for (int i = 0; i < NPT; ++i) {
        const float4 d = *reinterpret_cast<const float4*>(dboxes + (size_t)(n0 + i) * 4);
        ax1[i] = d.x; ay1[i] = d.y; ax2[i] = d.z; ay2[i] = d.w;
        aa[i]  = (d.z - d.x) * (d.w - d.y);
    }

    float* const irow = out_ious + (size_t)b * M1 * NANCH + n0;

    // ---- REAL pass (identical to R3) ----
    float best[NPT]; int besti[NPT];
    #pragma unroll
    for (int i = 0; i < NPT; ++i) { best[i] = -1.0f; besti[i] = 0; }

    auto row_body = [&](int m) {
        const float4 g = s_box[m];      // ds_read_b128 broadcast
        const float ga = s_ar[m];       // ds_read_b32 broadcast
        float iou[NPT];
        #pragma unroll
        for (int i = 0; i < NPT; ++i) {
            const float ix1 = fmaxf(g.x, ax1[i]), iy1 = fmaxf(g.y, ay1[i]);
            const float ix2 = fminf(g.z, ax2[i]), iy2 = fminf(g.w, ay2[i]);
            const float iw = fmaxf(ix2 - ix1, 0.0f), ih = fmaxf(iy2 - iy1, 0.0f);
            const float inter = iw * ih;
            iou[i] = inter * __builtin_amdgcn_rcpf(ga + aa[i] - inter);
            if (iou[i] > best[i]) { best[i] = iou[i]; besti[i] = m; }
        }
        float2 w; w.x = iou[0]; w.y = iou[1];
        *reinterpret_cast<float2*>(irow + (size_t)m * NANCH) = w;
    };

    for (int mg = 0; mg < MBULK; mg += GROUP) {
        #pragma unroll
        for (int r = 0; r < GROUP; ++r) row_body(mg + r);
    }
    #pragma unroll
    for (int r = 0; r < MTAIL; ++r) row_body(MBULK + r);

    // ---- DIAGNOSTIC tail: 3 compute-only replica passes (no stores). ----
    // Opaque z=0 per pass defeats cross-pass CSE; asm sinks defeat DCE.
    #pragma unroll 1
    for (int pass = 0; pass < 3; ++pass) {
        float z = 0.0f;
        asm volatile("" : "+v"(z));
        float zb[NPT]; int zbi[NPT];
        #pragma unroll
        for (int i = 0; i < NPT; ++i) { zb[i] = -1.0f; zbi[i] = 0; }
        #pragma unroll 4
        for (int m = 0; m < M1; ++m) {
            const float4 g = s_box[m];
            const float ga = s_ar[m] + z;         // z-perturbed: unique per pass
            #pragma unroll
            for (int i = 0; i < NPT; ++i) {
                const float ix1 = fmaxf(g.x, ax1[i]), iy1 = fmaxf(g.y, ay1[i]);
                const float ix2 = fminf(g.z, ax2[i]), iy2 = fminf(g.w, ay2[i]);
                const float iw = fmaxf(ix2 - ix1, 0.0f), ih = fmaxf(iy2 - iy1, 0.0f);
                const float inter = iw * ih;
                const float iou = inter * __builtin_amdgcn_rcpf(ga + aa[i] - inter);
                if (iou > zb[i]) { zb[i] = iou; zbi[i] = m; }
            }
        }
        #pragma unroll
        for (int i = 0; i < NPT; ++i)
            asm volatile("" :: "v"(zb[i]), "v"(zbi[i]));
    }

    // ---- Epilogue (uses REAL-pass argmax state) ----
    float lw[NPT * 5];
    #pragma unroll
    for (int i = 0; i < NPT; ++i) {
        const int idx = (best[i] > 0.5f) ? besti[i] : 0;
        float ox = 0.f, oy = 0.f, ow = 0.f, oh = 0.f, pcls = 0.f;
        if (idx != 0) {   // iou>0.5 winner is always a valid (cls!=0) row
            const float4 t = s_box[idx];
            const float aw = ax2[i] - ax1[i], ah = ay2[i] - ay1[i];
            ox = (0.5f * (t.x + t.z) - 0.5f * (ax1[i] + ax2[i])) / aw;
            oy = (0.5f * (t.y + t.w) - 0.5f * (ay1[i] + ay2[i])) / ah;
            ow = __logf((t.z - t.x) / aw);
            oh = __logf((t.w - t.y) / ah);
            pcls = s_cls[idx];
        }
        lw[i * 5 + 0] = ox; lw[i * 5 + 1] = oy; lw[i * 5 + 2] = ow;
        lw[i * 5 + 3] = oh; lw[i * 5 + 4] = pcls;
    }
    float* lrow = out_labeled + ((size_t)b * NANCH + n0) * 5;
    #pragma unroll
    for (int k = 0; k < 5; ++k) {
        float2 v; v.x = lw[k * 2]; v.y = lw[k * 2 + 1];
        *reinterpret_cast<float2*>(lrow + k * 2) = v;
    }
}

extern "C" void kernel_launch(void* const* d_in, const int* in_sizes, int n_in,
                              void* d_out, int out_size, void* d_ws, size_t ws_size,
                              hipStream_t stream) {
    const float* labels = (const float*)d_in[0];
    const float* dboxes = (const float*)d_in[1];
    float* out_labeled = (float*)d_out;
    float* out_ious    = out_labeled + (size_t)BATCH * NANCH * 5;

    encode_fused<<<dim3(NBLK), dim3(BLOCK), 0, stream>>>(labels, dboxes, out_labeled, out_ious);
}

// Round 7
// 240.833 us; speedup vs baseline: 1.3191x; 1.3191x over previous
//
#include <hip/hip_runtime.h>

#define BATCH 64
#define M_GT  100
#define M1    101
#define NANCH 8732
#define BLOCK 256
#define NPT   2                    // anchors per thread -> dwordx2 stores
#define NTILE (BLOCK * NPT)        // 512
#define NX    18                   // ceil(8732/512)
#define NBLK  (NX * BATCH)         // 1152 blocks = 4608 waves
#define NXCD  8
#define GR    16                   // rows per compute/store phase
#define MBULK ((M1 / GR) * GR)     // 96
#define MTAIL (M1 - MBULK)         // 5

// Journal:
//  R0: NPT=4, 576 blocks                    -> 245.7 (baseline)
//  R1: NPT=2, depth-8 groups, 1152 blocks   -> 244.4 neutral
//  R2: nontemporal stores                   -> 279.3 REGRESSION (L2 merge load-bearing)
//  R3: XCD-grouping swizzle                 -> 240.4 (+4, best)
//  R4: role-split contiguous row writer     -> 265.8 REGRESSION (contiguity not the lever)
//  R5: double compute+store pass            -> 264.8 (marginal pass = 24.4 µs; output L3-resident)
//  R6: +3 compute-only passes (diagnostic)  -> kernel row: VALUBusy 83%, FETCH ~1 MB,
//      WRITE 233 MB @ 6.3 TB/s drain. Single-pass kernel ~67 µs = VALU 30 + drain 37,
//      SERIALIZED: per-row [compute][store] in-order streams stall compute behind
//      backpressured stores; store-free VALU overlaps fine (83% proof).
//  R7 (this): phase split. [compute GR=16 rows -> regs][burst 16 stores].
//      Long store-free compute windows let the CU scheduler overlap one wave's
//      VALU with другой's store burst. Everything else identical to R3.
__global__ __launch_bounds__(BLOCK) void encode_fused(
    const float* __restrict__ labels,   // [B, M, 5]
    const float* __restrict__ dboxes,   // [N, 4]
    float* __restrict__ out_labeled,    // [B, N, 5]
    float* __restrict__ out_ious)       // [B, M1, N]
{
    __shared__ float4 s_box[M1];
    __shared__ float  s_ar[M1], s_cls[M1];

    const int tid = threadIdx.x;
    // XCD-grouping swizzle (R3): all NX chunks of each b on one XCD.
    const int x  = blockIdx.x % NXCD;
    const int j  = blockIdx.x / NXCD;
    const int b  = x * (BATCH / NXCD) + j / NX;
    const int nb = j % NX;

    if (tid < M1) {
        float x1 = 0.f, y1 = 0.f, x2 = 0.f, y2 = 0.f, cls = 0.f;
        float ar = __builtin_inff();   // pad/invalid -> iou = inter*rcp(inf) = +0
        if (tid >= 1) {
            const float* row = labels + ((size_t)b * M_GT + (tid - 1)) * 5;
            x1 = row[0]; y1 = row[1]; x2 = row[2]; y2 = row[3]; cls = row[4];
            if (cls != 0.0f) ar = (x2 - x1) * (y2 - y1);
        }
        s_box[tid] = make_float4(x1, y1, x2, y2);
        s_ar[tid] = ar; s_cls[tid] = cls;
    }
    __syncthreads();

    const int n0 = nb * NTILE + tid * NPT;
    if (n0 >= NANCH) return;

    float ax1[NPT], ay1[NPT], ax2[NPT], ay2[NPT], aa[NPT];
    #pragma unroll
    for (int i = 0; i < NPT; ++i) {
        const float4 d = *reinterpret_cast<const float4*>(dboxes + (size_t)(n0 + i) * 4);
        ax1[i] = d.x; ay1[i] = d.y; ax2[i] = d.z; ay2[i] = d.w;
        aa[i]  = (d.z - d.x) * (d.w - d.y);
    }

    float* const irow = out_ious + (size_t)b * M1 * NANCH + n0;

    // best=-1: pad rows give iou=+0; strict > = numpy first-occurrence argmax.
    float best[NPT]; int besti[NPT];
    #pragma unroll
    for (int i = 0; i < NPT; ++i) { best[i] = -1.0f; besti[i] = 0; }

    // Compute one row m into a float2 (and update argmax). Static r indexing
    // only (rule #20): called from fully-unrolled loops.
    auto compute_row = [&](int m, float2& res) {
        const float4 g = s_box[m];      // ds_read_b128 broadcast
        const float ga = s_ar[m];       // ds_read_b32 broadcast
        float iou[NPT];
        #pragma unroll
        for (int i = 0; i < NPT; ++i) {
            const float ix1 = fmaxf(g.x, ax1[i]), iy1 = fmaxf(g.y, ay1[i]);
            const float ix2 = fminf(g.z, ax2[i]), iy2 = fminf(g.w, ay2[i]);
            const float iw = fmaxf(ix2 - ix1, 0.0f), ih = fmaxf(iy2 - iy1, 0.0f);
            const float inter = iw * ih;
            iou[i] = inter * __builtin_amdgcn_rcpf(ga + aa[i] - inter);  // validated R3/R7
            if (iou[i] > best[i]) { best[i] = iou[i]; besti[i] = m; }
        }
        res.x = iou[0]; res.y = iou[1];
    };

    // Bulk: 6 phases of [compute 16 -> regs][store 16].
    #pragma unroll 1
    for (int mg = 0; mg < MBULK; mg += GR) {
        float2 res[GR];
        #pragma unroll
        for (int r = 0; r < GR; ++r) compute_row(mg + r, res[r]);
        #pragma unroll
        for (int r = 0; r < GR; ++r)
            *reinterpret_cast<float2*>(irow + (size_t)(mg + r) * NANCH) = res[r];
    }
    // Tail: 5 rows, same phase pattern.
    {
        float2 res[MTAIL];
        #pragma unroll
        for (int r = 0; r < MTAIL; ++r) compute_row(MBULK + r, res[r]);
        #pragma unroll
        for (int r = 0; r < MTAIL; ++r)
            *reinterpret_cast<float2*>(irow + (size_t)(MBULK + r) * NANCH) = res[r];
    }

    // Epilogue
    float lw[NPT * 5];
    #pragma unroll
    for (int i = 0; i < NPT; ++i) {
        const int idx = (best[i] > 0.5f) ? besti[i] : 0;
        float ox = 0.f, oy = 0.f, ow = 0.f, oh = 0.f, pcls = 0.f;
        if (idx != 0) {   // iou>0.5 winner is always a valid (cls!=0) row
            const float4 t = s_box[idx];
            const float aw = ax2[i] - ax1[i], ah = ay2[i] - ay1[i];
            ox = (0.5f * (t.x + t.z) - 0.5f * (ax1[i] + ax2[i])) / aw;
            oy = (0.5f * (t.y + t.w) - 0.5f * (ay1[i] + ay2[i])) / ah;
            ow = __logf((t.z - t.x) / aw);
            oh = __logf((t.w - t.y) / ah);
            pcls = s_cls[idx];
        }
        lw[i * 5 + 0] = ox; lw[i * 5 + 1] = oy; lw[i * 5 + 2] = ow;
        lw[i * 5 + 3] = oh; lw[i * 5 + 4] = pcls;
    }
    // 10 contiguous floats = 40B, 8B-aligned (n0 even) -> 5 dwordx2 stores
    float* lrow = out_labeled + ((size_t)b * NANCH + n0) * 5;
    #pragma unroll
    for (int k = 0; k < 5; ++k) {
        float2 v; v.x = lw[k * 2]; v.y = lw[k * 2 + 1];
        *reinterpret_cast<float2*>(lrow + k * 2) = v;
    }
}

extern "C" void kernel_launch(void* const* d_in, const int* in_sizes, int n_in,
                              void* d_out, int out_size, void* d_ws, size_t ws_size,
                              hipStream_t stream) {
    const float* labels = (const float*)d_in[0];
    const float* dboxes = (const float*)d_in[1];
    float* out_labeled = (float*)d_out;
    float* out_ious    = out_labeled + (size_t)BATCH * NANCH * 5;

    encode_fused<<<dim3(NBLK), dim3(BLOCK), 0, stream>>>(labels, dboxes, out_labeled, out_ious);
}